// Round 6
// baseline (209.191 us; speedup 1.0000x reference)
//
#include <hip/hip_runtime.h>

// N-gram embedding mean on gfx950. One wave per word.
// Two rows per vmem instruction: float4 x 32 lanes = 512B row; wave half 0
// loads even slots, half 1 odd slots -> 1KB per global_load_dwordx4 issue,
// 12 gather instructions instead of 24. Row ids are wave-uniform SGPRs
// (readfirstlane with full wave active); per-half row select is a per-lane
// cndmask (no shuffles in any divergent region). Final cross-half fold via
// __shfl_xor(.,32) with the full wave active. Group skips on cnt are
// wave-uniform. Padding rows (id 0) loaded but masked via fmaf (L1-hot).
#define NUM_WORDS 32768   // B*S = 16*2048
#define KMAX 24

__global__ __launch_bounds__(256) void ngram_emb_kernel(
    const int* __restrict__ word_idx,      // [B*S]
    const int* __restrict__ ngram_ids,     // [V, K]
    const int* __restrict__ ngram_counts,  // [V]
    const float* __restrict__ emb_table,   // [NG, E]
    float* __restrict__ out)               // [B*S, E]
{
    const int gtid = blockIdx.x * blockDim.x + threadIdx.x;
    const int word = gtid >> 6;            // one wave per word
    const int lane = threadIdx.x & 63;
    const int half = lane >> 5;            // 0: even slots, 1: odd slots
    const int l32  = lane & 31;            // float4 chunk within the 512B row

    // wave-uniform scalars (full wave active -> readfirstlane safe)
    const int w   = __builtin_amdgcn_readfirstlane(word_idx[word]);
    const int cnt = ngram_counts[w];       // uniform scalar load
    const int* ids = ngram_ids + w * KMAX;

    int rr[KMAX];
#pragma unroll
    for (int k = 0; k < KMAX; ++k)
        rr[k] = __builtin_amdgcn_readfirstlane(ids[k]);

    const float4* tbl = (const float4*)emb_table;   // row stride = 32 float4

    // ---- phase 1: issue all gathers (2 rows per instruction) ----
    float4 v[12];
#pragma unroll
    for (int j = 0; j < 4; ++j) {
        const int r = half ? rr[2 * j + 1] : rr[2 * j];
        v[j] = tbl[(long)r * 32 + l32];
    }
    if (cnt > 8) {
#pragma unroll
        for (int j = 4; j < 8; ++j) {
            const int r = half ? rr[2 * j + 1] : rr[2 * j];
            v[j] = tbl[(long)r * 32 + l32];
        }
    }
    if (cnt > 16) {
#pragma unroll
        for (int j = 8; j < 12; ++j) {
            const int r = half ? rr[2 * j + 1] : rr[2 * j];
            v[j] = tbl[(long)r * 32 + l32];
        }
    }

    // ---- phase 2: masked accumulate ----
    float4 s = make_float4(0.f, 0.f, 0.f, 0.f);
#pragma unroll
    for (int j = 0; j < 4; ++j) {
        const int r = half ? rr[2 * j + 1] : rr[2 * j];
        const float m = r ? 1.f : 0.f;
        s.x = fmaf(m, v[j].x, s.x); s.y = fmaf(m, v[j].y, s.y);
        s.z = fmaf(m, v[j].z, s.z); s.w = fmaf(m, v[j].w, s.w);
    }
    if (cnt > 8) {
#pragma unroll
        for (int j = 4; j < 8; ++j) {
            const int r = half ? rr[2 * j + 1] : rr[2 * j];
            const float m = r ? 1.f : 0.f;
            s.x = fmaf(m, v[j].x, s.x); s.y = fmaf(m, v[j].y, s.y);
            s.z = fmaf(m, v[j].z, s.z); s.w = fmaf(m, v[j].w, s.w);
        }
    }
    if (cnt > 16) {
#pragma unroll
        for (int j = 8; j < 12; ++j) {
            const int r = half ? rr[2 * j + 1] : rr[2 * j];
            const float m = r ? 1.f : 0.f;
            s.x = fmaf(m, v[j].x, s.x); s.y = fmaf(m, v[j].y, s.y);
            s.z = fmaf(m, v[j].z, s.z); s.w = fmaf(m, v[j].w, s.w);
        }
    }

    // ---- fold odd-slot half into even-slot half (full wave active) ----
    s.x += __shfl_xor(s.x, 32);
    s.y += __shfl_xor(s.y, 32);
    s.z += __shfl_xor(s.z, 32);
    s.w += __shfl_xor(s.w, 32);

    if (half == 0) {
        const float inv = 1.0f / (float)cnt;
        float4 o = make_float4(s.x * inv, s.y * inv, s.z * inv, s.w * inv);
        ((float4*)out)[(long)word * 32 + l32] = o;  // 32 lanes x 16B = 512B
    }
}

extern "C" void kernel_launch(void* const* d_in, const int* in_sizes, int n_in,
                              void* d_out, int out_size, void* d_ws, size_t ws_size,
                              hipStream_t stream) {
    const int*   word_idx     = (const int*)d_in[0];
    const int*   ngram_ids    = (const int*)d_in[1];
    const int*   ngram_counts = (const int*)d_in[2];
    const float* emb_table    = (const float*)d_in[3];
    float*       out          = (float*)d_out;

    const int threads = 256;
    const int blocks  = (NUM_WORDS * 64) / threads;  // 8192
    ngram_emb_kernel<<<blocks, threads, 0, stream>>>(
        word_idx, ngram_ids, ngram_counts, emb_table, out);
}

// Round 7
// 169.725 us; speedup vs baseline: 1.2325x; 1.2325x over previous
//
#include <hip/hip_runtime.h>

// N-gram embedding mean on gfx950. One wave per word (best-measured R3
// structure, VGPR-light, no spills) + non-temporal output stores.
// - word id & all 24 ngram ids pinned scalar via readfirstlane (full wave
//   active -> safe; saddr-form loads, zero VALU addressing).
// - slots in static groups of 8 with wave-uniform cnt skips; within a group
//   all 8 row loads (4KB) issue before any accumulate (R4's 24-deep hoist
//   measured neutral vs this; R6's float4 variant spilled -> 213MB scratch).
// - padding slots hit row 0 (L1-hot), masked branchless via fmaf.
// - output stored with nt hint: 16MB write stream skips L2 write-allocate,
//   preserving L2 capacity for the ~1.8x-reuse table gather stream.
#define NUM_WORDS 32768   // B*S = 16*2048
#define KMAX 24
#define GROUP 8

typedef float v2f __attribute__((ext_vector_type(2)));

__global__ __launch_bounds__(256) void ngram_emb_kernel(
    const int* __restrict__ word_idx,      // [B*S]
    const int* __restrict__ ngram_ids,     // [V, K]
    const int* __restrict__ ngram_counts,  // [V]
    const float* __restrict__ emb_table,   // [NG, E]
    float* __restrict__ out)               // [B*S, E]
{
    const int gtid = blockIdx.x * blockDim.x + threadIdx.x;
    const int word = gtid >> 6;            // one wave per word
    const int lane = threadIdx.x & 63;     // float2 chunk within the 512B row

    // wave-uniform scalars (full wave active -> readfirstlane safe)
    const int w   = __builtin_amdgcn_readfirstlane(word_idx[word]);
    const int cnt = ngram_counts[w];       // uniform scalar load
    const int* ids = ngram_ids + w * KMAX;

    int rr[KMAX];
#pragma unroll
    for (int k = 0; k < KMAX; ++k)
        rr[k] = __builtin_amdgcn_readfirstlane(ids[k]);

    const float2* tbl = (const float2*)emb_table;   // row stride = 64 float2
    float ax = 0.f, ay = 0.f;

#pragma unroll
    for (int g = 0; g < KMAX; g += GROUP) {
        if (g < cnt) {                      // uniform branch: skip empty groups
            float2 v[GROUP];
            float  m[GROUP];
#pragma unroll
            for (int j = 0; j < GROUP; ++j) {
                const int r = rr[g + j];    // scalar row id (0 = padding)
                m[j] = r ? 1.f : 0.f;
                v[j] = tbl[(long)r * 64 + lane];   // unconditional; row 0 L1-hot
            }
#pragma unroll
            for (int j = 0; j < GROUP; ++j) {
                ax = fmaf(m[j], v[j].x, ax);
                ay = fmaf(m[j], v[j].y, ay);
            }
        }
    }

    const float inv = 1.0f / (float)cnt;
    v2f o = { ax * inv, ay * inv };
    // 64 lanes x 8B = one contiguous 512B row; nt -> no L2 write-allocate
    __builtin_nontemporal_store(o, ((v2f*)out) + (long)word * 64 + lane);
}

extern "C" void kernel_launch(void* const* d_in, const int* in_sizes, int n_in,
                              void* d_out, int out_size, void* d_ws, size_t ws_size,
                              hipStream_t stream) {
    const int*   word_idx     = (const int*)d_in[0];
    const int*   ngram_ids    = (const int*)d_in[1];
    const int*   ngram_counts = (const int*)d_in[2];
    const float* emb_table    = (const float*)d_in[3];
    float*       out          = (float*)d_out;

    const int threads = 256;
    const int blocks  = (NUM_WORDS * 64) / threads;  // 8192
    ngram_emb_kernel<<<blocks, threads, 0, stream>>>(
        word_idx, ngram_ids, ngram_counts, emb_table, out);
}